// Round 9
// baseline (52.389 us; speedup 1.0000x reference)
//
#include <hip/hip_runtime.h>

#define N_ 2048
#define F_ 128

// workspace (u64 units)
#define WS_P1 0      // [8*64]        tagged per-block a_j partial sums
#define WS_P2 512    // [8*128*2*64]  tagged s-partials: P2[((b*128+c)*2+vec)*64 + kb]

typedef __attribute__((ext_vector_type(8))) short short8v;
typedef __attribute__((ext_vector_type(4))) float f32x4;
typedef unsigned long long u64;

__device__ inline short f2bf(float f) {
    union { float f; unsigned u; } c; c.f = f;
    unsigned r = (c.u + 0x7FFFu + ((c.u >> 16) & 1u)) >> 16;
    return (short)r;
}
__device__ inline void store_pair(u64* p, float f) {
    union { float f; unsigned u; } c; c.f = f;
    const u64 v = ((u64)(~c.u) << 32) | (u64)c.u;
    __hip_atomic_store(p, v, __ATOMIC_RELAXED, __HIP_MEMORY_SCOPE_AGENT);
}
__device__ inline bool pair_ok(u64 v) {
    return (unsigned)(v >> 32) == (unsigned)(~(unsigned)v);
}
__device__ inline float pair_val(u64 v) {
    union { unsigned u; float f; } c; c.u = (unsigned)v;
    return c.f;
}

// DEADLOCK RULE (learned r8): spin-barrier producer sets must be contiguous
// in blockIdx so reduced co-residency + in-order dispatch still progresses.
// b = bid>>6 keeps each batch's 64 producers in one contiguous bid chunk.
__global__ __launch_bounds__(256, 2) void gcn_one(
    const float* __restrict__ x, const float* __restrict__ adj_w,
    const float* __restrict__ adj_b_p, const float* __restrict__ weight,
    const float* __restrict__ bias, float* __restrict__ outx,
    u64* __restrict__ P1, u64* __restrict__ P2)
{
    __shared__ unsigned short wt[128 * 128];   // W^T bf16, slot-swizzled (32 KB)
    __shared__ float adjw[256];
    __shared__ float ail[32], ajl[32], disl[32], ajdl[32];
    __shared__ float red0[2][128], red1[2][128];
    __shared__ float s0l[128], s1l[128], bl[128];
    __shared__ float Ash;

    const int bid = blockIdx.x;                 // 0..511
    const int b = bid >> 6;                     // contiguous producer chunks!
    const int kbme = bid & 63;                  // 0..63
    const int r0 = kbme * 32;
    const int t = threadIdx.x;                  // 0..255
    const int lane = t & 63, w = t >> 6;        // 4 waves
    const int u = lane & 15, g = lane >> 4;
    const int wr = (w & 1) * 16;                // row-group (0 or 16)
    const int ct0 = (w >> 1) * 4;               // col-tile base (0 or 4)

    const float adjb = adj_b_p[0];              // hoisted uniform load
    adjw[t] = adj_w[t];
    if (t < 128) bl[t] = bias[t];
    __syncthreads();

    // ---- phase 1: read x ONCE in MFMA A-layout; a_i/a_j via in-lane + shfl
    const float* xrow = x + (size_t)(b * N_ + r0 + wr + u) * F_;
    float4 xa[4], xb[4];
    #pragma unroll
    for (int kk = 0; kk < 4; ++kk) {
        xa[kk] = *reinterpret_cast<const float4*>(xrow + kk * 32 + g * 8);
        xb[kk] = *reinterpret_cast<const float4*>(xrow + kk * 32 + g * 8 + 4);
    }
    {
        float ai = 0.f, aj = 0.f;
        #pragma unroll
        for (int kk = 0; kk < 4; ++kk) {
            const float va[4] = {xa[kk].x, xa[kk].y, xa[kk].z, xa[kk].w};
            const float vb[4] = {xb[kk].x, xb[kk].y, xb[kk].z, xb[kk].w};
            #pragma unroll
            for (int i = 0; i < 4; ++i) {
                const int k = kk * 32 + g * 8 + i;
                ai = fmaf(va[i], adjw[k], ai);
                aj = fmaf(va[i], adjw[128 + k], aj);
                ai = fmaf(vb[i], adjw[k + 4], ai);
                aj = fmaf(vb[i], adjw[128 + k + 4], aj);
            }
        }
        ai += __shfl_xor(ai, 16, 64); ai += __shfl_xor(ai, 32, 64);
        aj += __shfl_xor(aj, 16, 64); aj += __shfl_xor(aj, 32, 64);
        if (w < 2 && g == 0) {
            ail[wr + u] = ai + adjb;
            ajl[wr + u] = aj;
        }
    }
    __syncthreads();
    // block partial of sum(a_j) -> P1 (tagged), published ASAP
    if (t < 32) {
        float s = ajl[t];
        #pragma unroll
        for (int off = 16; off > 0; off >>= 1) s += __shfl_down(s, off, 64);
        if (t == 0) store_pair(&P1[b * 64 + kbme], s);
    }

    // ---- stage W^T bf16 (barrier-independent; hides P1 propagation)
    {
        const int c = t & 127, khalf = t >> 7;
        for (int j8 = 0; j8 < 8; ++j8) {
            const int kb = khalf * 8 + j8;
            short8v v;
            #pragma unroll
            for (int i = 0; i < 8; ++i)
                v[i] = f2bf(weight[(kb * 8 + i) * F_ + c]);
            const int slot = kb ^ (c & 15);
            *reinterpret_cast<short8v*>(&wt[c * 128 + slot * 8]) = v;
        }
    }
    __syncthreads();

    // ---- MFMA GEMM from registers (still barrier-independent)
    f32x4 acc[4];
    #pragma unroll
    for (int i = 0; i < 4; ++i) acc[i] = (f32x4)(0.f);
    #pragma unroll
    for (int kk = 0; kk < 4; ++kk) {
        short8v af;
        af[0] = f2bf(xa[kk].x); af[1] = f2bf(xa[kk].y);
        af[2] = f2bf(xa[kk].z); af[3] = f2bf(xa[kk].w);
        af[4] = f2bf(xb[kk].x); af[5] = f2bf(xb[kk].y);
        af[6] = f2bf(xb[kk].z); af[7] = f2bf(xb[kk].w);
        const int kb = kk * 4 + g;
        #pragma unroll
        for (int c = 0; c < 4; ++c) {
            const int col = (ct0 + c) * 16 + u;
            const int slot = kb ^ u;            // col&15 == u
            const short8v bfv = *reinterpret_cast<const short8v*>(&wt[col * 128 + slot * 8]);
            acc[c] = __builtin_amdgcn_mfma_f32_16x16x32_bf16(af, bfv, acc[c], 0, 0, 0);
        }
    }

    // ---- barrier A: spin on the 64 tagged P1 partials of this batch
    if (t < 64) {
        u64 v;
        while (true) {
            v = __hip_atomic_load(&P1[b * 64 + t], __ATOMIC_RELAXED, __HIP_MEMORY_SCOPE_AGENT);
            if (pair_ok(v)) break;
            __builtin_amdgcn_s_sleep(1);
        }
        float s = pair_val(v);
        #pragma unroll
        for (int off = 32; off > 0; off >>= 1) s += __shfl_down(s, off, 64);
        if (t == 0) Ash = s;
    }
    __syncthreads();
    if (t < 32) {
        const float deg = fmaxf(2048.f * ail[t] + Ash + 1.f, 1.f);
        const float d = rsqrtf(deg);
        disl[t] = d;
        ajdl[t] = ajl[t] * d;
    }
    __syncthreads();

    // ---- s-partials from MFMA accumulators (no x re-read, no matvec)
    #pragma unroll
    for (int c = 0; c < 4; ++c) {
        float s0 = 0.f, s1 = 0.f;
        #pragma unroll
        for (int r = 0; r < 4; ++r) {
            const int row = wr + g * 4 + r;
            s0 = fmaf(disl[row], acc[c][r], s0);
            s1 = fmaf(ajdl[row], acc[c][r], s1);
        }
        s0 += __shfl_xor(s0, 16, 64); s0 += __shfl_xor(s0, 32, 64);
        s1 += __shfl_xor(s1, 16, 64); s1 += __shfl_xor(s1, 32, 64);
        if (g == 0) {
            red0[w & 1][(ct0 + c) * 16 + u] = s0;
            red1[w & 1][(ct0 + c) * 16 + u] = s1;
        }
    }
    __syncthreads();
    // publish tagged s-partials: thread t -> (vec = t>>7, col = t&127)
    {
        const int c = t & 127, vec = t >> 7;
        const float v = (vec == 0) ? (red0[0][c] + red0[1][c])
                                   : (red1[0][c] + red1[1][c]);
        store_pair(&P2[((size_t)((b * 128 + c) * 2 + vec)) * 64 + kbme], v);
    }

    // ---- barrier B: direct gather of the 64 partials per (col,vec)
    {
        const int c = t & 127, vec = t >> 7;
        u64* base = &P2[((size_t)((b * 128 + c) * 2 + vec)) * 64];
        float s = 0.f;
        #pragma unroll 1
        for (int q = 0; q < 4; ++q) {
            u64 vv[16];
            bool ok;
            do {
                ok = true;
                #pragma unroll
                for (int i = 0; i < 16; ++i)
                    vv[i] = __hip_atomic_load(&base[q * 16 + i], __ATOMIC_RELAXED, __HIP_MEMORY_SCOPE_AGENT);
                #pragma unroll
                for (int i = 0; i < 16; ++i) ok &= pair_ok(vv[i]);
                if (!ok) __builtin_amdgcn_s_sleep(2);
            } while (!ok);
            #pragma unroll
            for (int i = 0; i < 16; ++i) s += pair_val(vv[i]);
        }
        if (vec == 0) s0l[c] = s; else s1l[c] = s;
    }
    __syncthreads();

    // ---- epilogue on MFMA accumulators, single out write
    #pragma unroll
    for (int c = 0; c < 4; ++c) {
        const int col = (ct0 + c) * 16 + u;
        const float sv0 = s0l[col], sv1 = s1l[col], bv = bl[col];
        #pragma unroll
        for (int r = 0; r < 4; ++r) {
            const int row = wr + g * 4 + r;
            const float d = disl[row], ab = ail[row];
            const float o = fmaxf(d * (ab * sv0 + sv1 + d * acc[c][r]) + bv, 0.f);
            outx[(size_t)(b * N_ + r0 + row) * F_ + col] = o;
        }
    }
}

extern "C" void kernel_launch(void* const* d_in, const int* in_sizes, int n_in,
                              void* d_out, int out_size, void* d_ws, size_t ws_size,
                              hipStream_t stream) {
    const float* x      = (const float*)d_in[0];
    const float* adj_w  = (const float*)d_in[1];
    const float* adj_b  = (const float*)d_in[2];
    const float* weight = (const float*)d_in[3];
    const float* bias   = (const float*)d_in[4];
    float* out = (float*)d_out;
    u64* ws = (u64*)d_ws;

    gcn_one<<<512, 256, 0, stream>>>(x, adj_w, adj_b, weight, bias, out,
                                     ws + WS_P1, ws + WS_P2);
}

// Round 10
// 22.953 us; speedup vs baseline: 2.2824x; 2.2824x over previous
//
#include <hip/hip_runtime.h>

#define N_ 2048
#define F_ 128

typedef __attribute__((ext_vector_type(8))) short short8v;
typedef __attribute__((ext_vector_type(4))) float f32x4;
typedef unsigned long long u64;

__device__ inline short f2bf(float f) {
    union { float f; unsigned u; } c; c.f = f;
    unsigned r = (c.u + 0x7FFFu + ((c.u >> 16) & 1u)) >> 16;
    return (short)r;
}
__device__ inline void store_pair(u64* p, float f) {
    union { float f; unsigned u; } c; c.f = f;
    const u64 v = ((u64)(~c.u) << 32) | (u64)c.u;
    __hip_atomic_store(p, v, __ATOMIC_RELAXED, __HIP_MEMORY_SCOPE_AGENT);
}
__device__ inline bool pair_ok(u64 v) {
    return (unsigned)(v >> 32) == (unsigned)(~(unsigned)v);
}
__device__ inline float pair_val(u64 v) {
    union { unsigned u; float f; } c; c.u = (unsigned)v;
    return c.f;
}

// ---------------- K1: a-rows, GEMM, dis, s-partials, pre-out ----------------
// grid 512 x 256. DEADLOCK RULE (r8): producer sets contiguous in blockIdx.
__global__ __launch_bounds__(256, 2) void k1_main(
    const float* __restrict__ x, const float* __restrict__ adj_w,
    const float* __restrict__ adj_b_p, const float* __restrict__ weight,
    float* __restrict__ outx,          // pre-epilogue out (d_out as scratch)
    u64* __restrict__ P1,              // [8*64] tagged a_j partials
    float* __restrict__ disW,          // [8*2048]
    float* __restrict__ aibW,          // [8*2048]
    float* __restrict__ P2f)           // [8][64][256] plain s-partials
{
    __shared__ unsigned short wt[128 * 128];   // W^T bf16, slot-swizzled (32 KB)
    __shared__ float adjw[256];
    __shared__ float ail[32], ajl[32], disl[32], ajdl[32];
    __shared__ float red0[2][128], red1[2][128];
    __shared__ float Ash;

    const int bid = blockIdx.x;                 // 0..511
    const int b = bid >> 6;                     // contiguous producer chunks
    const int kbme = bid & 63;
    const int r0 = kbme * 32;
    const int t = threadIdx.x;
    const int lane = t & 63, w = t >> 6;
    const int u = lane & 15, g = lane >> 4;
    const int wr = (w & 1) * 16;
    const int ct0 = (w >> 1) * 4;

    const float adjb = adj_b_p[0];
    adjw[t] = adj_w[t];
    __syncthreads();

    // ---- phase 1: read x ONCE in MFMA A-layout; a_i/a_j via in-lane + shfl
    const float* xrow = x + (size_t)(b * N_ + r0 + wr + u) * F_;
    float4 xa[4], xb[4];
    #pragma unroll
    for (int kk = 0; kk < 4; ++kk) {
        xa[kk] = *reinterpret_cast<const float4*>(xrow + kk * 32 + g * 8);
        xb[kk] = *reinterpret_cast<const float4*>(xrow + kk * 32 + g * 8 + 4);
    }
    {
        float ai = 0.f, aj = 0.f;
        #pragma unroll
        for (int kk = 0; kk < 4; ++kk) {
            const float va[4] = {xa[kk].x, xa[kk].y, xa[kk].z, xa[kk].w};
            const float vb[4] = {xb[kk].x, xb[kk].y, xb[kk].z, xb[kk].w};
            #pragma unroll
            for (int i = 0; i < 4; ++i) {
                const int k = kk * 32 + g * 8 + i;
                ai = fmaf(va[i], adjw[k], ai);
                aj = fmaf(va[i], adjw[128 + k], aj);
                ai = fmaf(vb[i], adjw[k + 4], ai);
                aj = fmaf(vb[i], adjw[128 + k + 4], aj);
            }
        }
        ai += __shfl_xor(ai, 16, 64); ai += __shfl_xor(ai, 32, 64);
        aj += __shfl_xor(aj, 16, 64); aj += __shfl_xor(aj, 32, 64);
        if (w < 2 && g == 0) {
            ail[wr + u] = ai + adjb;
            ajl[wr + u] = aj;
        }
    }
    __syncthreads();
    // publish tagged a_j partial ASAP
    if (t < 32) {
        float s = ajl[t];
        #pragma unroll
        for (int off = 16; off > 0; off >>= 1) s += __shfl_down(s, off, 64);
        if (t == 0) store_pair(&P1[b * 64 + kbme], s);
    }

    // ---- stage W^T bf16 (barrier-independent; hides P1 propagation)
    {
        const int c = t & 127, khalf = t >> 7;
        for (int j8 = 0; j8 < 8; ++j8) {
            const int kb = khalf * 8 + j8;
            short8v v;
            #pragma unroll
            for (int i = 0; i < 8; ++i)
                v[i] = f2bf(weight[(kb * 8 + i) * F_ + c]);
            const int slot = kb ^ (c & 15);
            *reinterpret_cast<short8v*>(&wt[c * 128 + slot * 8]) = v;
        }
    }
    __syncthreads();

    // ---- MFMA GEMM from registers (barrier-independent)
    f32x4 acc[4];
    #pragma unroll
    for (int i = 0; i < 4; ++i) acc[i] = (f32x4)(0.f);
    #pragma unroll
    for (int kk = 0; kk < 4; ++kk) {
        short8v af;
        af[0] = f2bf(xa[kk].x); af[1] = f2bf(xa[kk].y);
        af[2] = f2bf(xa[kk].z); af[3] = f2bf(xa[kk].w);
        af[4] = f2bf(xb[kk].x); af[5] = f2bf(xb[kk].y);
        af[6] = f2bf(xb[kk].z); af[7] = f2bf(xb[kk].w);
        const int kb = kk * 4 + g;
        #pragma unroll
        for (int c = 0; c < 4; ++c) {
            const int col = (ct0 + c) * 16 + u;
            const int slot = kb ^ u;            // col&15 == u
            const short8v bfv = *reinterpret_cast<const short8v*>(&wt[col * 128 + slot * 8]);
            acc[c] = __builtin_amdgcn_mfma_f32_16x16x32_bf16(af, bfv, acc[c], 0, 0, 0);
        }
    }

    // ---- pre-epilogue out write (overlaps barrier-A skew)
    #pragma unroll
    for (int c = 0; c < 4; ++c) {
        const int col = (ct0 + c) * 16 + u;
        #pragma unroll
        for (int r = 0; r < 4; ++r) {
            const int row = wr + g * 4 + r;
            outx[(size_t)(b * N_ + r0 + row) * F_ + col] = acc[c][r];
        }
    }

    // ---- barrier A: spin on the 64 tagged P1 partials of this batch
    if (t < 64) {
        u64 v;
        while (true) {
            v = __hip_atomic_load(&P1[b * 64 + t], __ATOMIC_RELAXED, __HIP_MEMORY_SCOPE_AGENT);
            if (pair_ok(v)) break;
            __builtin_amdgcn_s_sleep(1);
        }
        float s = pair_val(v);
        #pragma unroll
        for (int off = 32; off > 0; off >>= 1) s += __shfl_down(s, off, 64);
        if (t == 0) Ash = s;
    }
    __syncthreads();
    if (t < 32) {
        const float deg = fmaxf(2048.f * ail[t] + Ash + 1.f, 1.f);
        const float d = rsqrtf(deg);
        disl[t] = d;
        ajdl[t] = ajl[t] * d;
        disW[b * N_ + r0 + t] = d;
        aibW[b * N_ + r0 + t] = ail[t];
    }
    __syncthreads();

    // ---- s-partials from accumulators (rows of this block), plain publish
    #pragma unroll
    for (int c = 0; c < 4; ++c) {
        float s0 = 0.f, s1 = 0.f;
        #pragma unroll
        for (int r = 0; r < 4; ++r) {
            const int row = wr + g * 4 + r;
            s0 = fmaf(disl[row], acc[c][r], s0);
            s1 = fmaf(ajdl[row], acc[c][r], s1);
        }
        s0 += __shfl_xor(s0, 16, 64); s0 += __shfl_xor(s0, 32, 64);
        s1 += __shfl_xor(s1, 16, 64); s1 += __shfl_xor(s1, 32, 64);
        if (g == 0) {
            red0[w & 1][(ct0 + c) * 16 + u] = s0;
            red1[w & 1][(ct0 + c) * 16 + u] = s1;
        }
    }
    __syncthreads();
    // coalesced plain-float publish: cv = t (0..127 s0, 128..255 s1)
    {
        const int c = t & 127;
        const float v = (t < 128) ? (red0[0][c] + red0[1][c])
                                  : (red1[0][c] + red1[1][c]);
        P2f[(size_t)(b * 64 + kbme) * 256 + t] = v;
    }
}

// ---------------- K2: reduce s-partials, epilogue in place ----------------
// grid 256 x 512 (32 blocks/batch, 64 rows each)
__global__ __launch_bounds__(512) void k2_epi(
    const float* __restrict__ P2f, const float* __restrict__ disW,
    const float* __restrict__ aibW, const float* __restrict__ bias,
    float* __restrict__ outx)
{
    __shared__ float red[2][256];
    __shared__ float s0l[128], s1l[128], bl[128], disl[64], aibl[64];

    const int bid = blockIdx.x;
    const int b = bid >> 5, r0 = (bid & 31) * 64;
    const int t = threadIdx.x;                  // 0..511

    // gather-reduce: cv = t&255, half = t>>8 covers 32 kb each (coalesced)
    {
        const int cv = t & 255, half = t >> 8;
        const float* p = P2f + (size_t)(b * 64 + half * 32) * 256 + cv;
        float s = 0.f;
        #pragma unroll 8
        for (int i = 0; i < 32; ++i) s += p[(size_t)i * 256];
        red[half][cv] = s;
    }
    if (t >= 256 && t < 320) disl[t - 256] = disW[b * N_ + r0 + (t - 256)];
    else if (t >= 320 && t < 384) aibl[t - 320] = aibW[b * N_ + r0 + (t - 320)];
    else if (t >= 384) bl[t - 384] = bias[t - 384];
    __syncthreads();
    if (t < 128) s0l[t] = red[0][t] + red[1][t];
    else if (t < 256) s1l[t - 128] = red[0][t] + red[1][t];
    __syncthreads();

    // epilogue: thread -> row r0 + (t>>3), cols (t&7)*16..+15 (4x float4)
    {
        const int r = t >> 3, c0 = (t & 7) * 16;
        const float d = disl[r], ab = aibl[r];
        float* op = outx + (size_t)(b * N_ + r0 + r) * F_ + c0;
        #pragma unroll
        for (int ii = 0; ii < 4; ++ii) {
            const int c = c0 + ii * 4;
            float4 o = *reinterpret_cast<const float4*>(op + ii * 4);
            o.x = fmaxf(d * (ab * s0l[c]     + s1l[c]     + d * o.x) + bl[c],     0.f);
            o.y = fmaxf(d * (ab * s0l[c + 1] + s1l[c + 1] + d * o.y) + bl[c + 1], 0.f);
            o.z = fmaxf(d * (ab * s0l[c + 2] + s1l[c + 2] + d * o.z) + bl[c + 2], 0.f);
            o.w = fmaxf(d * (ab * s0l[c + 3] + s1l[c + 3] + d * o.w) + bl[c + 3], 0.f);
            *reinterpret_cast<float4*>(op + ii * 4) = o;
        }
    }
}

extern "C" void kernel_launch(void* const* d_in, const int* in_sizes, int n_in,
                              void* d_out, int out_size, void* d_ws, size_t ws_size,
                              hipStream_t stream) {
    const float* x      = (const float*)d_in[0];
    const float* adj_w  = (const float*)d_in[1];
    const float* adj_b  = (const float*)d_in[2];
    const float* weight = (const float*)d_in[3];
    const float* bias   = (const float*)d_in[4];
    float* out = (float*)d_out;

    u64*   P1   = (u64*)d_ws;                          // 512 * 8B
    float* wsf  = (float*)((char*)d_ws + 4096);
    float* disW = wsf;                                 // 16384
    float* aibW = wsf + 16384;                         // 16384
    float* P2f  = wsf + 32768;                         // 8*64*256 = 131072

    k1_main<<<512, 256, 0, stream>>>(x, adj_w, adj_b, weight, out,
                                     P1, disW, aibW, P2f);
    k2_epi<<<256, 512, 0, stream>>>(P2f, disW, aibW, bias, out);
}

// Round 11
// 20.814 us; speedup vs baseline: 2.5170x; 1.1028x over previous
//
#include <hip/hip_runtime.h>

#define N_ 2048
#define F_ 128

// workspace (u64 units)
#define WS_P1 0      // [8*64]         tagged per-block a_j partial sums
#define WS_P2 512    // [8][64][128][2] tagged s-partials: P2[((b*64+kb)*128+c)*2+vec]
                     //  (kb-major: gather is wave-coalesced — r9 lesson!)

typedef __attribute__((ext_vector_type(8))) short short8v;
typedef __attribute__((ext_vector_type(4))) float f32x4;
typedef unsigned long long u64;

__device__ inline short f2bf(float f) {
    union { float f; unsigned u; } c; c.f = f;
    unsigned r = (c.u + 0x7FFFu + ((c.u >> 16) & 1u)) >> 16;
    return (short)r;
}
__device__ inline void store_pair(u64* p, float f) {
    union { float f; unsigned u; } c; c.f = f;
    const u64 v = ((u64)(~c.u) << 32) | (u64)c.u;
    __hip_atomic_store(p, v, __ATOMIC_RELAXED, __HIP_MEMORY_SCOPE_AGENT);
}
__device__ inline bool pair_ok(u64 v) {
    return (unsigned)(v >> 32) == (unsigned)(~(unsigned)v);
}
__device__ inline float pair_val(u64 v) {
    union { unsigned u; float f; } c; c.u = (unsigned)v;
    return c.f;
}

// DEADLOCK RULE (r8): spin-barrier producer sets must be contiguous in
// blockIdx (b = bid>>6) so partial co-residency still makes progress.
// LAYOUT RULE (r9): P2 must be kb-major so the gather is wave-coalesced.
__global__ __launch_bounds__(256, 2) void gcn_one(
    const float* __restrict__ x, const float* __restrict__ adj_w,
    const float* __restrict__ adj_b_p, const float* __restrict__ weight,
    const float* __restrict__ bias, float* __restrict__ outx,
    u64* __restrict__ P1, u64* __restrict__ P2)
{
    __shared__ unsigned short wt[128 * 128];   // W^T bf16, slot-swizzled (32 KB)
    __shared__ float adjw[256];
    __shared__ float ail[32], ajl[32], disl[32], ajdl[32];
    __shared__ float red0[2][128], red1[2][128];
    __shared__ float s0l[128], s1l[128], bl[128];
    __shared__ float Ash;

    const int bid = blockIdx.x;                 // 0..511
    const int b = bid >> 6;                     // contiguous producer chunks
    const int kbme = bid & 63;                  // 0..63
    const int r0 = kbme * 32;
    const int t = threadIdx.x;                  // 0..255
    const int lane = t & 63, w = t >> 6;        // 4 waves
    const int u = lane & 15, g = lane >> 4;
    const int wr = (w & 1) * 16;                // row-group (0 or 16)
    const int ct0 = (w >> 1) * 4;               // col-tile base (0 or 4)

    const float adjb = adj_b_p[0];
    adjw[t] = adj_w[t];
    if (t < 128) bl[t] = bias[t];
    __syncthreads();

    // ---- phase 1: read x ONCE in MFMA A-layout; a_i/a_j via in-lane + shfl
    const float* xrow = x + (size_t)(b * N_ + r0 + wr + u) * F_;
    float4 xa[4], xb[4];
    #pragma unroll
    for (int kk = 0; kk < 4; ++kk) {
        xa[kk] = *reinterpret_cast<const float4*>(xrow + kk * 32 + g * 8);
        xb[kk] = *reinterpret_cast<const float4*>(xrow + kk * 32 + g * 8 + 4);
    }
    {
        float ai = 0.f, aj = 0.f;
        #pragma unroll
        for (int kk = 0; kk < 4; ++kk) {
            const float va[4] = {xa[kk].x, xa[kk].y, xa[kk].z, xa[kk].w};
            const float vb[4] = {xb[kk].x, xb[kk].y, xb[kk].z, xb[kk].w};
            #pragma unroll
            for (int i = 0; i < 4; ++i) {
                const int k = kk * 32 + g * 8 + i;
                ai = fmaf(va[i], adjw[k], ai);
                aj = fmaf(va[i], adjw[128 + k], aj);
                ai = fmaf(vb[i], adjw[k + 4], ai);
                aj = fmaf(vb[i], adjw[128 + k + 4], aj);
            }
        }
        ai += __shfl_xor(ai, 16, 64); ai += __shfl_xor(ai, 32, 64);
        aj += __shfl_xor(aj, 16, 64); aj += __shfl_xor(aj, 32, 64);
        if (w < 2 && g == 0) {
            ail[wr + u] = ai + adjb;
            ajl[wr + u] = aj;
        }
    }
    __syncthreads();
    // publish tagged a_j partial ASAP
    if (t < 32) {
        float s = ajl[t];
        #pragma unroll
        for (int off = 16; off > 0; off >>= 1) s += __shfl_down(s, off, 64);
        if (t == 0) store_pair(&P1[b * 64 + kbme], s);
    }

    // ---- stage W^T bf16 (barrier-independent; hides P1 propagation)
    {
        const int c = t & 127, khalf = t >> 7;
        for (int j8 = 0; j8 < 8; ++j8) {
            const int kb = khalf * 8 + j8;
            short8v v;
            #pragma unroll
            for (int i = 0; i < 8; ++i)
                v[i] = f2bf(weight[(kb * 8 + i) * F_ + c]);
            const int slot = kb ^ (c & 15);
            *reinterpret_cast<short8v*>(&wt[c * 128 + slot * 8]) = v;
        }
    }
    __syncthreads();

    // ---- MFMA GEMM from registers (still barrier-independent)
    f32x4 acc[4];
    #pragma unroll
    for (int i = 0; i < 4; ++i) acc[i] = (f32x4)(0.f);
    #pragma unroll
    for (int kk = 0; kk < 4; ++kk) {
        short8v af;
        af[0] = f2bf(xa[kk].x); af[1] = f2bf(xa[kk].y);
        af[2] = f2bf(xa[kk].z); af[3] = f2bf(xa[kk].w);
        af[4] = f2bf(xb[kk].x); af[5] = f2bf(xb[kk].y);
        af[6] = f2bf(xb[kk].z); af[7] = f2bf(xb[kk].w);
        const int kb = kk * 4 + g;
        #pragma unroll
        for (int c = 0; c < 4; ++c) {
            const int col = (ct0 + c) * 16 + u;
            const int slot = kb ^ u;            // col&15 == u
            const short8v bfv = *reinterpret_cast<const short8v*>(&wt[col * 128 + slot * 8]);
            acc[c] = __builtin_amdgcn_mfma_f32_16x16x32_bf16(af, bfv, acc[c], 0, 0, 0);
        }
    }

    // ---- barrier A: spin on the 64 tagged P1 partials of this batch
    if (t < 64) {
        u64 v;
        while (true) {
            v = __hip_atomic_load(&P1[b * 64 + t], __ATOMIC_RELAXED, __HIP_MEMORY_SCOPE_AGENT);
            if (pair_ok(v)) break;
            __builtin_amdgcn_s_sleep(1);
        }
        float s = pair_val(v);
        #pragma unroll
        for (int off = 32; off > 0; off >>= 1) s += __shfl_down(s, off, 64);
        if (t == 0) Ash = s;
    }
    __syncthreads();
    if (t < 32) {
        const float deg = fmaxf(2048.f * ail[t] + Ash + 1.f, 1.f);
        const float d = rsqrtf(deg);
        disl[t] = d;
        ajdl[t] = ajl[t] * d;
    }
    __syncthreads();

    // ---- s-partials DIRECTLY from MFMA accumulators (no x re-read, no matvec)
    #pragma unroll
    for (int c = 0; c < 4; ++c) {
        float s0 = 0.f, s1 = 0.f;
        #pragma unroll
        for (int r = 0; r < 4; ++r) {
            const int row = wr + g * 4 + r;
            s0 = fmaf(disl[row], acc[c][r], s0);
            s1 = fmaf(ajdl[row], acc[c][r], s1);
        }
        s0 += __shfl_xor(s0, 16, 64); s0 += __shfl_xor(s0, 32, 64);
        s1 += __shfl_xor(s1, 16, 64); s1 += __shfl_xor(s1, 32, 64);
        if (g == 0) {
            red0[w & 1][(ct0 + c) * 16 + u] = s0;
            red1[w & 1][(ct0 + c) * 16 + u] = s1;
        }
    }
    __syncthreads();
    // publish tagged s-partials, kb-major layout (r5's proven-coalesced form):
    // thread t<128 -> col t, both vecs, adjacent records
    if (t < 128) {
        const size_t rec = ((size_t)(b * 64 + kbme) * 128 + t) * 2;
        store_pair(&P2[rec],     red0[0][t] + red0[1][t]);
        store_pair(&P2[rec + 1], red1[0][t] + red1[1][t]);
    }

    // ---- barrier B: wave-coalesced gather of 64 kb-partials per (col,vec)
    // thread (c = t&127, kh = t>>7): kh covers kb 0..31 / 32..63
    {
        const int c = t & 127, kh = t >> 7;
        float s0 = 0.f, s1 = 0.f;
        #pragma unroll 1
        for (int kb0 = 0; kb0 < 32; kb0 += 8) {
            u64 v0[8], v1[8];
            bool ok;
            do {
                ok = true;
                #pragma unroll
                for (int i = 0; i < 8; ++i) {
                    const size_t rec = ((size_t)(b * 64 + kh * 32 + kb0 + i) * 128 + c) * 2;
                    v0[i] = __hip_atomic_load(&P2[rec], __ATOMIC_RELAXED, __HIP_MEMORY_SCOPE_AGENT);
                    v1[i] = __hip_atomic_load(&P2[rec + 1], __ATOMIC_RELAXED, __HIP_MEMORY_SCOPE_AGENT);
                }
                #pragma unroll
                for (int i = 0; i < 8; ++i) ok &= pair_ok(v0[i]) & pair_ok(v1[i]);
                if (!ok) __builtin_amdgcn_s_sleep(2);
            } while (!ok);
            #pragma unroll
            for (int i = 0; i < 8; ++i) { s0 += pair_val(v0[i]); s1 += pair_val(v1[i]); }
        }
        red0[kh][c] = s0;
        red1[kh][c] = s1;
    }
    __syncthreads();
    if (t < 128) s0l[t] = red0[0][t] + red0[1][t];
    else { const int c = t - 128; s1l[c] = red1[0][c] + red1[1][c]; }
    __syncthreads();

    // ---- epilogue on MFMA accumulators, single out write
    #pragma unroll
    for (int c = 0; c < 4; ++c) {
        const int col = (ct0 + c) * 16 + u;
        const float sv0 = s0l[col], sv1 = s1l[col], bv = bl[col];
        #pragma unroll
        for (int r = 0; r < 4; ++r) {
            const int row = wr + g * 4 + r;
            const float d = disl[row], ab = ail[row];
            const float o = fmaxf(d * (ab * sv0 + sv1 + d * acc[c][r]) + bv, 0.f);
            outx[(size_t)(b * N_ + r0 + row) * F_ + col] = o;
        }
    }
}

extern "C" void kernel_launch(void* const* d_in, const int* in_sizes, int n_in,
                              void* d_out, int out_size, void* d_ws, size_t ws_size,
                              hipStream_t stream) {
    const float* x      = (const float*)d_in[0];
    const float* adj_w  = (const float*)d_in[1];
    const float* adj_b  = (const float*)d_in[2];
    const float* weight = (const float*)d_in[3];
    const float* bias   = (const float*)d_in[4];
    float* out = (float*)d_out;
    u64* ws = (u64*)d_ws;

    gcn_one<<<512, 256, 0, stream>>>(x, adj_w, adj_b, weight, bias, out,
                                     ws + WS_P1, ws + WS_P2);
}

// Round 12
// 18.130 us; speedup vs baseline: 2.8896x; 1.1480x over previous
//
#include <hip/hip_runtime.h>

#define N_ 2048
#define F_ 128

// workspace (u64 units)
#define WS_P1 0      // [8*64]          tagged per-block a_j partial sums
#define WS_SF 512    // [8*256]         tagged finals per (batch, cv)  (cv = 2c+vec)
#define WS_P2 2560   // [8][64][256]    tagged s-partials: P2[(b*64+kb)*256 + cv]
                     //  kb-major: stage-1 publish is wave-coalesced (r9 lesson)

typedef __attribute__((ext_vector_type(8))) short short8v;
typedef __attribute__((ext_vector_type(4))) float f32x4;
typedef unsigned long long u64;

__device__ inline short f2bf(float f) {
    union { float f; unsigned u; } c; c.f = f;
    unsigned r = (c.u + 0x7FFFu + ((c.u >> 16) & 1u)) >> 16;
    return (short)r;
}
__device__ inline void store_pair(u64* p, float f) {
    union { float f; unsigned u; } c; c.f = f;
    const u64 v = ((u64)(~c.u) << 32) | (u64)c.u;
    __hip_atomic_store(p, v, __ATOMIC_RELAXED, __HIP_MEMORY_SCOPE_AGENT);
}
__device__ inline bool pair_ok(u64 v) {
    return (unsigned)(v >> 32) == (unsigned)(~(unsigned)v);
}
__device__ inline float pair_val(u64 v) {
    union { unsigned u; float f; } c; c.u = (unsigned)v;
    return c.f;
}

// DEADLOCK RULE (r8): spin producer sets contiguous in blockIdx (b = bid>>6).
// LAYOUT RULE (r9): publishes and gathers must be wave-coalesced.
// TREE RULE (r6→r12): reduction hops are fine only if maximally parallel —
// here every block finalizes 4 cv with exactly 1 record per thread.
__global__ __launch_bounds__(256, 2) void gcn_one(
    const float* __restrict__ x, const float* __restrict__ adj_w,
    const float* __restrict__ adj_b_p, const float* __restrict__ weight,
    const float* __restrict__ bias, float* __restrict__ outx,
    u64* __restrict__ P1, u64* __restrict__ SF, u64* __restrict__ P2)
{
    __shared__ unsigned short wt[128 * 128];   // W^T bf16, slot-swizzled (32 KB)
    __shared__ float adjw[256];
    __shared__ float ail[32], ajl[32], disl[32], ajdl[32];
    __shared__ float red0[2][128], red1[2][128];
    __shared__ float s0l[128], s1l[128], bl[128];
    __shared__ float Ash;

    const int bid = blockIdx.x;                 // 0..511
    const int b = bid >> 6;                     // contiguous producer chunks
    const int kbme = bid & 63;                  // 0..63
    const int r0 = kbme * 32;
    const int t = threadIdx.x;                  // 0..255
    const int lane = t & 63, w = t >> 6;        // 4 waves
    const int u = lane & 15, g = lane >> 4;
    const int wr = (w & 1) * 16;                // row-group (0 or 16)
    const int ct0 = (w >> 1) * 4;               // col-tile base (0 or 4)

    const float adjb = adj_b_p[0];
    adjw[t] = adj_w[t];
    if (t < 128) bl[t] = bias[t];
    __syncthreads();

    // ---- phase 1: read x ONCE in MFMA A-layout; a_i/a_j via in-lane + shfl
    const float* xrow = x + (size_t)(b * N_ + r0 + wr + u) * F_;
    float4 xa[4], xb[4];
    #pragma unroll
    for (int kk = 0; kk < 4; ++kk) {
        xa[kk] = *reinterpret_cast<const float4*>(xrow + kk * 32 + g * 8);
        xb[kk] = *reinterpret_cast<const float4*>(xrow + kk * 32 + g * 8 + 4);
    }
    {
        float ai = 0.f, aj = 0.f;
        #pragma unroll
        for (int kk = 0; kk < 4; ++kk) {
            const float va[4] = {xa[kk].x, xa[kk].y, xa[kk].z, xa[kk].w};
            const float vb[4] = {xb[kk].x, xb[kk].y, xb[kk].z, xb[kk].w};
            #pragma unroll
            for (int i = 0; i < 4; ++i) {
                const int k = kk * 32 + g * 8 + i;
                ai = fmaf(va[i], adjw[k], ai);
                aj = fmaf(va[i], adjw[128 + k], aj);
                ai = fmaf(vb[i], adjw[k + 4], ai);
                aj = fmaf(vb[i], adjw[128 + k + 4], aj);
            }
        }
        ai += __shfl_xor(ai, 16, 64); ai += __shfl_xor(ai, 32, 64);
        aj += __shfl_xor(aj, 16, 64); aj += __shfl_xor(aj, 32, 64);
        if (w < 2 && g == 0) {
            ail[wr + u] = ai + adjb;
            ajl[wr + u] = aj;
        }
    }
    __syncthreads();
    // publish tagged a_j partial ASAP
    if (t < 32) {
        float s = ajl[t];
        #pragma unroll
        for (int off = 16; off > 0; off >>= 1) s += __shfl_down(s, off, 64);
        if (t == 0) store_pair(&P1[b * 64 + kbme], s);
    }

    // ---- stage W^T bf16 (barrier-independent; hides P1 propagation)
    {
        const int c = t & 127, khalf = t >> 7;
        for (int j8 = 0; j8 < 8; ++j8) {
            const int kb = khalf * 8 + j8;
            short8v v;
            #pragma unroll
            for (int i = 0; i < 8; ++i)
                v[i] = f2bf(weight[(kb * 8 + i) * F_ + c]);
            const int slot = kb ^ (c & 15);
            *reinterpret_cast<short8v*>(&wt[c * 128 + slot * 8]) = v;
        }
    }
    __syncthreads();

    // ---- MFMA GEMM from registers (still barrier-independent)
    f32x4 acc[4];
    #pragma unroll
    for (int i = 0; i < 4; ++i) acc[i] = (f32x4)(0.f);
    #pragma unroll
    for (int kk = 0; kk < 4; ++kk) {
        short8v af;
        af[0] = f2bf(xa[kk].x); af[1] = f2bf(xa[kk].y);
        af[2] = f2bf(xa[kk].z); af[3] = f2bf(xa[kk].w);
        af[4] = f2bf(xb[kk].x); af[5] = f2bf(xb[kk].y);
        af[6] = f2bf(xb[kk].z); af[7] = f2bf(xb[kk].w);
        const int kb = kk * 4 + g;
        #pragma unroll
        for (int c = 0; c < 4; ++c) {
            const int col = (ct0 + c) * 16 + u;
            const int slot = kb ^ u;            // col&15 == u
            const short8v bfv = *reinterpret_cast<const short8v*>(&wt[col * 128 + slot * 8]);
            acc[c] = __builtin_amdgcn_mfma_f32_16x16x32_bf16(af, bfv, acc[c], 0, 0, 0);
        }
    }

    // ---- barrier A: spin on the 64 tagged P1 partials of this batch
    if (t < 64) {
        u64 v;
        while (true) {
            v = __hip_atomic_load(&P1[b * 64 + t], __ATOMIC_RELAXED, __HIP_MEMORY_SCOPE_AGENT);
            if (pair_ok(v)) break;
            __builtin_amdgcn_s_sleep(1);
        }
        float s = pair_val(v);
        #pragma unroll
        for (int off = 32; off > 0; off >>= 1) s += __shfl_down(s, off, 64);
        if (t == 0) Ash = s;
    }
    __syncthreads();
    if (t < 32) {
        const float deg = fmaxf(2048.f * ail[t] + Ash + 1.f, 1.f);
        const float d = rsqrtf(deg);
        disl[t] = d;
        ajdl[t] = ajl[t] * d;
    }
    __syncthreads();

    // ---- s-partials DIRECTLY from MFMA accumulators
    #pragma unroll
    for (int c = 0; c < 4; ++c) {
        float s0 = 0.f, s1 = 0.f;
        #pragma unroll
        for (int r = 0; r < 4; ++r) {
            const int row = wr + g * 4 + r;
            s0 = fmaf(disl[row], acc[c][r], s0);
            s1 = fmaf(ajdl[row], acc[c][r], s1);
        }
        s0 += __shfl_xor(s0, 16, 64); s0 += __shfl_xor(s0, 32, 64);
        s1 += __shfl_xor(s1, 16, 64); s1 += __shfl_xor(s1, 32, 64);
        if (g == 0) {
            red0[w & 1][(ct0 + c) * 16 + u] = s0;
            red1[w & 1][(ct0 + c) * 16 + u] = s1;
        }
    }
    __syncthreads();
    // ---- stage 1 publish: all 256 threads, coalesced (cv = t, c = t>>1)
    {
        const int c = t >> 1;
        const float v = (t & 1) ? (red1[0][c] + red1[1][c])
                                : (red0[0][c] + red0[1][c]);
        store_pair(&P2[(size_t)(b * 64 + kbme) * 256 + t], v);
    }

    // ---- stage 2: this block finalizes cv = kbme*4 + w (1 record per thread)
    {
        const int cv = kbme * 4 + w;
        u64 v;
        while (true) {
            v = __hip_atomic_load(&P2[(size_t)(b * 64 + lane) * 256 + cv],
                                  __ATOMIC_RELAXED, __HIP_MEMORY_SCOPE_AGENT);
            if (pair_ok(v)) break;
            __builtin_amdgcn_s_sleep(1);
        }
        float s = pair_val(v);
        #pragma unroll
        for (int off = 32; off > 0; off >>= 1) s += __shfl_down(s, off, 64);
        if (lane == 0) store_pair(&SF[b * 256 + cv], s);
    }

    // ---- stage 3: spin on the 256 finals (2 KB), land in s0l/s1l
    {
        u64 v;
        while (true) {
            v = __hip_atomic_load(&SF[b * 256 + t], __ATOMIC_RELAXED, __HIP_MEMORY_SCOPE_AGENT);
            if (pair_ok(v)) break;
            __builtin_amdgcn_s_sleep(1);
        }
        const float sv = pair_val(v);
        if ((t & 1) == 0) s0l[t >> 1] = sv; else s1l[t >> 1] = sv;
    }
    __syncthreads();

    // ---- epilogue on MFMA accumulators, single out write
    #pragma unroll
    for (int c = 0; c < 4; ++c) {
        const int col = (ct0 + c) * 16 + u;
        const float sv0 = s0l[col], sv1 = s1l[col], bv = bl[col];
        #pragma unroll
        for (int r = 0; r < 4; ++r) {
            const int row = wr + g * 4 + r;
            const float d = disl[row], ab = ail[row];
            const float o = fmaxf(d * (ab * sv0 + sv1 + d * acc[c][r]) + bv, 0.f);
            outx[(size_t)(b * N_ + r0 + row) * F_ + col] = o;
        }
    }
}

extern "C" void kernel_launch(void* const* d_in, const int* in_sizes, int n_in,
                              void* d_out, int out_size, void* d_ws, size_t ws_size,
                              hipStream_t stream) {
    const float* x      = (const float*)d_in[0];
    const float* adj_w  = (const float*)d_in[1];
    const float* adj_b  = (const float*)d_in[2];
    const float* weight = (const float*)d_in[3];
    const float* bias   = (const float*)d_in[4];
    float* out = (float*)d_out;
    u64* ws = (u64*)d_ws;

    gcn_one<<<512, 256, 0, stream>>>(x, adj_w, adj_b, weight, bias, out,
                                     ws + WS_P1, ws + WS_SF, ws + WS_P2);
}